// Round 1
// baseline (239.943 us; speedup 1.0000x reference)
//
#include <hip/hip_runtime.h>
#include <math.h>

#define B 8
#define C 4
#define H 512
#define W 512
#define SEL 1
#define BIGV 1024.0f   // H + W
#define NPIX (B*H*W)
#define NPART 2048

// ---------------- stats init ----------------
// stats layout per batch: [posmin, posmax, negmin, negmax] as bit-cast uints of d2 (>=0)
__global__ void init_stats(unsigned* __restrict__ stats) {
    int t = threadIdx.x;
    if (t < B * 4) {
        bool ismin = ((t & 1) == 0);          // idx 0,2 = mins
        stats[t] = ismin ? 0x7F800000u : 0u;  // +inf / 0
    }
}

// ---------------- vertical two-scan pass ----------------
// one thread per (which, batch, column); writes g (forward), then g^2 (backward) in place
__global__ void col_pass(const float* __restrict__ ytrue,
                         float* __restrict__ g2pos,
                         float* __restrict__ g2neg) {
    int t = blockIdx.x * blockDim.x + threadIdx.x;
    if (t >= 2 * B * W) return;
    int which = t / (B * W);          // 0 = mask, 1 = ~mask
    int r = t - which * (B * W);
    int b = r / W;
    int j = r - b * W;

    const float* m = ytrue + ((size_t)b * C + SEL) * H * W + j;
    float* g = (which ? g2neg : g2pos) + (size_t)b * H * W + j;

    float prev = BIGV;
    for (int i = 0; i < H; ++i) {
        float mv = m[(size_t)i * W];
        bool fg = (mv != 0.0f);
        if (which) fg = !fg;
        float gi = fg ? BIGV : 0.0f;
        gi = fminf(gi, prev + 1.0f);
        g[(size_t)i * W] = gi;
        prev = gi;
    }
    prev = BIGV;
    for (int i = H - 1; i >= 0; --i) {
        float gi = g[(size_t)i * W];
        gi = fminf(gi, prev + 1.0f);
        prev = gi;
        g[(size_t)i * W] = gi * gi;   // store squared
    }
}

// ---------------- exact row EDT (windowed outward scan) + min/max reduce ----------------
// one block (512 threads) per (which, batch, row); d2 written in place over g2
__global__ void row_edt(float* __restrict__ g2pos,
                        float* __restrict__ g2neg,
                        unsigned* __restrict__ stats) {
    __shared__ float row[W];
    __shared__ float smn[8], smx[8];

    int blk = blockIdx.x;                 // 0 .. 2*B*H-1
    int which = blk / (B * H);
    int rr = blk - which * (B * H);
    int b = rr / H;
    int i = rr - b * H;

    float* buf = (which ? g2neg : g2pos) + ((size_t)b * H + i) * W;
    int j = threadIdx.x;
    float g2 = buf[j];
    row[j] = g2;
    __syncthreads();

    float best = g2;
    for (int r = 1; r < W; ++r) {
        float r2 = (float)(r * r);
        if (r2 >= best) break;            // exact termination: further k can't improve
        int jl = j - r, jr = j + r;
        if (jl >= 0) best = fminf(best, row[jl] + r2);
        if (jr < W)  best = fminf(best, row[jr] + r2);
    }
    buf[j] = best;                        // d2 in place

    // block min/max of d2
    float mn = best, mx = best;
    for (int off = 32; off >= 1; off >>= 1) {
        mn = fminf(mn, __shfl_down(mn, off));
        mx = fmaxf(mx, __shfl_down(mx, off));
    }
    int wave = threadIdx.x >> 6, lane = threadIdx.x & 63;
    if (lane == 0) { smn[wave] = mn; smx[wave] = mx; }
    __syncthreads();
    if (threadIdx.x == 0) {
        float a = smn[0], bx = smx[0];
        #pragma unroll
        for (int w = 1; w < 8; ++w) { a = fminf(a, smn[w]); bx = fmaxf(bx, smx[w]); }
        unsigned* s = stats + b * 4 + (which ? 2 : 0);
        atomicMin(s,     __float_as_uint(a));
        atomicMax(s + 1, __float_as_uint(bx));
    }
}

// ---------------- fused sdf + boundary + sigmoid-sum + reduction ----------------
__global__ void final_reduce(const float* __restrict__ ypred,
                             const float* __restrict__ ytrue,
                             const float* __restrict__ d2pos,
                             const float* __restrict__ d2neg,
                             const unsigned* __restrict__ stats,
                             double* __restrict__ partials) {
    __shared__ float sacc[4];
    int tid = blockIdx.x * blockDim.x + threadIdx.x;
    int stride = gridDim.x * blockDim.x;
    float local = 0.f;
    for (int p = tid; p < NPIX; p += stride) {
        int b = p / (H * W);
        int ij = p - b * (H * W);
        int i = ij / W;
        int j = ij - i * W;

        float posdis = sqrtf(d2pos[p]);
        float negdis = sqrtf(d2neg[p]);
        float pmin = sqrtf(__uint_as_float(stats[b * 4 + 0]));
        float pmax = sqrtf(__uint_as_float(stats[b * 4 + 1]));
        float nmin = sqrtf(__uint_as_float(stats[b * 4 + 2]));
        float nmax = sqrtf(__uint_as_float(stats[b * 4 + 3]));
        float invp = (pmax > pmin) ? 1.0f / (pmax - pmin) : 0.0f;
        float invn = (nmax > nmin) ? 1.0f / (nmax - nmin) : 0.0f;
        float sdf = (negdis - nmin) * invn - (posdis - pmin) * invp;

        // inner boundary (pad = True outside image): fg pixel with an in-image bg 4-neighbor
        const float* m = ytrue + ((size_t)b * C + SEL) * H * W;
        bool c = m[ij] != 0.f;
        if (c) {
            bool l = (j == 0)     ? true : (m[ij - 1] != 0.f);
            bool r = (j == W - 1) ? true : (m[ij + 1] != 0.f);
            bool u = (i == 0)     ? true : (m[ij - W] != 0.f);
            bool d = (i == H - 1) ? true : (m[ij + W] != 0.f);
            if (!(l && r && u && d)) sdf = 0.f;
        }

        const float* yp = ypred + (size_t)b * C * H * W + ij;
        float s = 0.f;
        #pragma unroll
        for (int cc = 0; cc < C; ++cc) {
            float x = yp[(size_t)cc * H * W];
            s += 1.0f / (1.0f + expf(-x));
        }
        local += s * sdf;
    }
    // block reduce (f32 within block, double partial per block -> deterministic)
    for (int off = 32; off >= 1; off >>= 1) local += __shfl_down(local, off);
    int wave = threadIdx.x >> 6, lane = threadIdx.x & 63;
    if (lane == 0) sacc[wave] = local;
    __syncthreads();
    if (threadIdx.x == 0) {
        float tot = sacc[0] + sacc[1] + sacc[2] + sacc[3];
        partials[blockIdx.x] = (double)tot;
    }
}

__global__ void finalize(const double* __restrict__ partials, float* __restrict__ out) {
    __shared__ double sd[4];
    double s = 0.0;
    for (int p = threadIdx.x; p < NPART; p += blockDim.x) s += partials[p];
    for (int off = 32; off >= 1; off >>= 1) s += __shfl_down(s, off);
    int wave = threadIdx.x >> 6, lane = threadIdx.x & 63;
    if (lane == 0) sd[wave] = s;
    __syncthreads();
    if (threadIdx.x == 0) {
        double t = sd[0] + sd[1] + sd[2] + sd[3];
        out[0] = (float)(t / (double)((size_t)B * C * H * W));
    }
}

extern "C" void kernel_launch(void* const* d_in, const int* in_sizes, int n_in,
                              void* d_out, int out_size, void* d_ws, size_t ws_size,
                              hipStream_t stream) {
    const float* ypred = (const float*)d_in[0];
    const float* ytrue = (const float*)d_in[1];
    float* out = (float*)d_out;

    float* g2pos = (float*)d_ws;                 // NPIX floats (becomes d2pos)
    float* g2neg = g2pos + NPIX;                 // NPIX floats (becomes d2neg)
    unsigned* stats = (unsigned*)(g2neg + NPIX); // B*4 uints
    double* partials = (double*)(stats + B * 4); // NPART doubles (offset 8B-aligned)

    init_stats<<<1, 64, 0, stream>>>(stats);
    col_pass<<<(2 * B * W + 255) / 256, 256, 0, stream>>>(ytrue, g2pos, g2neg);
    row_edt<<<2 * B * H, W, 0, stream>>>(g2pos, g2neg, stats);
    final_reduce<<<NPART, 256, 0, stream>>>(ypred, ytrue, g2pos, g2neg, stats, partials);
    finalize<<<1, 256, 0, stream>>>(partials, out);
}

// Round 2
// 109.170 us; speedup vs baseline: 2.1979x; 2.1979x over previous
//
#include <hip/hip_runtime.h>
#include <math.h>

#define B 8
#define C 4
#define H 512
#define W 512
#define SEL 1
#define BIGV 1024.0f   // H + W
#define NPIX (B*H*W)
#define NPART 2048

// ---------------- vertical two-scan pass ----------------
// one thread per (which, batch, column); writes g (forward), then g^2 (backward) in place
__global__ void col_pass(const float* __restrict__ ytrue,
                         float* __restrict__ g2pos,
                         float* __restrict__ g2neg) {
    int t = blockIdx.x * blockDim.x + threadIdx.x;
    if (t >= 2 * B * W) return;
    int which = t / (B * W);          // 0 = mask, 1 = ~mask
    int r = t - which * (B * W);
    int b = r / W;
    int j = r - b * W;

    const float* m = ytrue + ((size_t)b * C + SEL) * H * W + j;
    float* g = (which ? g2neg : g2pos) + (size_t)b * H * W + j;

    float prev = BIGV;
    for (int i = 0; i < H; ++i) {
        float mv = m[(size_t)i * W];
        bool fg = (mv != 0.0f);
        if (which) fg = !fg;
        float gi = fg ? BIGV : 0.0f;
        gi = fminf(gi, prev + 1.0f);
        g[(size_t)i * W] = gi;
        prev = gi;
    }
    prev = BIGV;
    for (int i = H - 1; i >= 0; --i) {
        float gi = g[(size_t)i * W];
        gi = fminf(gi, prev + 1.0f);
        prev = gi;
        g[(size_t)i * W] = gi * gi;   // store squared
    }
}

// ---------------- exact row EDT (windowed outward scan) + per-block min/max ----------------
// one block (512 threads) per (which, batch, row); d2 written in place over g2.
// NO global atomics: per-block (min,max) goes to rowmm[blk].
__global__ void row_edt(float* __restrict__ g2pos,
                        float* __restrict__ g2neg,
                        float* __restrict__ rowmm) {
    __shared__ float row[W];
    __shared__ float smn[8], smx[8];

    int blk = blockIdx.x;                 // 0 .. 2*B*H-1
    int which = blk / (B * H);
    int rr = blk - which * (B * H);
    int b = rr / H;
    int i = rr - b * H;

    float* buf = (which ? g2neg : g2pos) + ((size_t)b * H + i) * W;
    int j = threadIdx.x;
    float g2 = buf[j];
    row[j] = g2;
    __syncthreads();

    float best = g2;
    for (int r = 1; r < W; ++r) {
        float r2 = (float)(r * r);
        if (r2 >= best) break;            // exact termination: further k can't improve
        int jl = j - r, jr = j + r;
        if (jl >= 0) best = fminf(best, row[jl] + r2);
        if (jr < W)  best = fminf(best, row[jr] + r2);
    }
    buf[j] = best;                        // d2 in place

    // block min/max of d2
    float mn = best, mx = best;
    for (int off = 32; off >= 1; off >>= 1) {
        mn = fminf(mn, __shfl_down(mn, off));
        mx = fmaxf(mx, __shfl_down(mx, off));
    }
    int wave = threadIdx.x >> 6, lane = threadIdx.x & 63;
    if (lane == 0) { smn[wave] = mn; smx[wave] = mx; }
    __syncthreads();
    if (threadIdx.x == 0) {
        float a = smn[0], bx = smx[0];
        #pragma unroll
        for (int w = 1; w < 8; ++w) { a = fminf(a, smn[w]); bx = fmaxf(bx, smx[w]); }
        rowmm[blk * 2]     = a;
        rowmm[blk * 2 + 1] = bx;
    }
}

// ---------------- per-(which,batch) stats: sqrt(min) and 1/(sqrt(max)-sqrt(min)) ----------------
// 16 blocks of 512 threads; block = which*B + b; thread t = row i.
// stats layout per batch (floats): [pmin, invp, nmin, invn]
__global__ void stats_reduce(const float* __restrict__ rowmm,
                             float* __restrict__ stats) {
    __shared__ float smn[8], smx[8];
    int which = blockIdx.x >> 3;
    int b = blockIdx.x & 7;
    int t = threadIdx.x;
    int base = ((which * B + b) * H + t) * 2;
    float mn = rowmm[base], mx = rowmm[base + 1];
    for (int off = 32; off >= 1; off >>= 1) {
        mn = fminf(mn, __shfl_down(mn, off));
        mx = fmaxf(mx, __shfl_down(mx, off));
    }
    int wave = t >> 6, lane = t & 63;
    if (lane == 0) { smn[wave] = mn; smx[wave] = mx; }
    __syncthreads();
    if (t == 0) {
        float a = smn[0], bx = smx[0];
        #pragma unroll
        for (int w = 1; w < 8; ++w) { a = fminf(a, smn[w]); bx = fmaxf(bx, smx[w]); }
        float dmin = sqrtf(a), dmax = sqrtf(bx);
        float inv = (dmax > dmin) ? 1.0f / (dmax - dmin) : 0.0f;
        stats[b * 4 + which * 2]     = dmin;
        stats[b * 4 + which * 2 + 1] = inv;
    }
}

// ---------------- fused sdf + boundary + sigmoid-sum + reduction ----------------
__global__ void final_reduce(const float* __restrict__ ypred,
                             const float* __restrict__ ytrue,
                             const float* __restrict__ d2pos,
                             const float* __restrict__ d2neg,
                             const float* __restrict__ stats,
                             double* __restrict__ partials) {
    __shared__ float sacc[4];
    int tid = blockIdx.x * blockDim.x + threadIdx.x;
    int stride = gridDim.x * blockDim.x;
    float local = 0.f;
    for (int p = tid; p < NPIX; p += stride) {
        int b = p / (H * W);
        int ij = p - b * (H * W);
        int i = ij / W;
        int j = ij - i * W;

        float posdis = sqrtf(d2pos[p]);
        float negdis = sqrtf(d2neg[p]);
        float pmin = stats[b * 4 + 0];
        float invp = stats[b * 4 + 1];
        float nmin = stats[b * 4 + 2];
        float invn = stats[b * 4 + 3];
        float sdf = (negdis - nmin) * invn - (posdis - pmin) * invp;

        // inner boundary (pad = True outside image): fg pixel with an in-image bg 4-neighbor
        const float* m = ytrue + ((size_t)b * C + SEL) * H * W;
        bool c = m[ij] != 0.f;
        if (c) {
            bool l = (j == 0)     ? true : (m[ij - 1] != 0.f);
            bool r = (j == W - 1) ? true : (m[ij + 1] != 0.f);
            bool u = (i == 0)     ? true : (m[ij - W] != 0.f);
            bool d = (i == H - 1) ? true : (m[ij + W] != 0.f);
            if (!(l && r && u && d)) sdf = 0.f;
        }

        const float* yp = ypred + (size_t)b * C * H * W + ij;
        float s = 0.f;
        #pragma unroll
        for (int cc = 0; cc < C; ++cc) {
            float x = yp[(size_t)cc * H * W];
            s += 1.0f / (1.0f + expf(-x));
        }
        local += s * sdf;
    }
    // block reduce (f32 within block, double partial per block -> deterministic)
    for (int off = 32; off >= 1; off >>= 1) local += __shfl_down(local, off);
    int wave = threadIdx.x >> 6, lane = threadIdx.x & 63;
    if (lane == 0) sacc[wave] = local;
    __syncthreads();
    if (threadIdx.x == 0) {
        float tot = sacc[0] + sacc[1] + sacc[2] + sacc[3];
        partials[blockIdx.x] = (double)tot;
    }
}

__global__ void finalize(const double* __restrict__ partials, float* __restrict__ out) {
    __shared__ double sd[4];
    double s = 0.0;
    for (int p = threadIdx.x; p < NPART; p += blockDim.x) s += partials[p];
    for (int off = 32; off >= 1; off >>= 1) s += __shfl_down(s, off);
    int wave = threadIdx.x >> 6, lane = threadIdx.x & 63;
    if (lane == 0) sd[wave] = s;
    __syncthreads();
    if (threadIdx.x == 0) {
        double t = sd[0] + sd[1] + sd[2] + sd[3];
        out[0] = (float)(t / (double)((size_t)B * C * H * W));
    }
}

extern "C" void kernel_launch(void* const* d_in, const int* in_sizes, int n_in,
                              void* d_out, int out_size, void* d_ws, size_t ws_size,
                              hipStream_t stream) {
    const float* ypred = (const float*)d_in[0];
    const float* ytrue = (const float*)d_in[1];
    float* out = (float*)d_out;

    float* g2pos = (float*)d_ws;                  // NPIX floats (becomes d2pos)
    float* g2neg = g2pos + NPIX;                  // NPIX floats (becomes d2neg)
    float* stats = g2neg + NPIX;                  // B*4 floats {pmin,invp,nmin,invn}
    float* rowmm = stats + B * 4;                 // 2*B*H*2 floats per-rowblock (mn,mx)
    double* partials = (double*)(rowmm + 2 * B * H * 2); // NPART doubles (8B-aligned)

    col_pass<<<(2 * B * W + 255) / 256, 256, 0, stream>>>(ytrue, g2pos, g2neg);
    row_edt<<<2 * B * H, W, 0, stream>>>(g2pos, g2neg, rowmm);
    stats_reduce<<<16, W, 0, stream>>>(rowmm, stats);
    final_reduce<<<NPART, 256, 0, stream>>>(ypred, ytrue, g2pos, g2neg, stats, partials);
    finalize<<<1, 256, 0, stream>>>(partials, out);
}

// Round 3
// 50.208 us; speedup vs baseline: 4.7790x; 2.1744x over previous
//
#include <hip/hip_runtime.h>
#include <math.h>

#define B 8
#define C 4
#define H 512
#define W 512
#define SEL 1
#define BIGI 1024       // H + W
#define NPIX (B*H*W)
#define NPART 2048

// ---------------- segmented vertical EDT pass (exact min-plus scan) ----------------
// block = TC columns x NSEG segments of L rows; one block per (which, b, col-tile)
#define L 32
#define NSEG 16
#define TC 32

__global__ __launch_bounds__(512) void col_pass_seg(const float* __restrict__ ytrue,
                                                    float* __restrict__ g2pos,
                                                    float* __restrict__ g2neg) {
    __shared__ int sA[NSEG][TC];   // lf -> D
    __shared__ int sB[NSEG][TC];   // lb -> U

    int blk = blockIdx.x;              // 2 * B * (W/TC) = 256
    int which = blk >> 7;              // / (B * 16)
    int rem = blk & 127;
    int b = rem >> 4;
    int jt = rem & 15;
    int tx = threadIdx.x & (TC - 1);
    int ty = threadIdx.x / TC;
    int j = jt * TC + tx;
    int i0 = ty * L;

    const float* m = ytrue + ((size_t)b * C + SEL) * H * W + j;
    float* out = (which ? g2neg : g2pos) + (size_t)b * H * W + j;

    // local forward scan (registers, statically indexed)
    int gf[L];
    int prev = BIGI;
    #pragma unroll
    for (int r = 0; r < L; ++r) {
        float mv = m[(size_t)(i0 + r) * W];
        bool fg = (mv != 0.0f);
        if (which) fg = !fg;
        int f = fg ? BIGI : 0;
        int v = min(f, prev + 1);
        gf[r] = v;
        prev = v;
    }
    sA[ty][tx] = prev;                 // local forward value at segment's last row
    __syncthreads();
    if (ty == 0) {                     // per-column forward carry scan over segments
        int d = BIGI;
        #pragma unroll
        for (int s = 0; s < NSEG; ++s) {
            d = min(sA[s][tx], d + L);
            sA[s][tx] = d;             // D[s]: resolved fwd value at last row of seg s
        }
    }
    __syncthreads();
    int carry = (ty == 0) ? BIGI : sA[ty - 1][tx];
    int lb = 0x7FFFFFFF;
    #pragma unroll
    for (int r = 0; r < L; ++r) {      // fix forward + local backward summary
        int v = min(gf[r], carry + 1 + r);
        gf[r] = v;
        lb = min(lb, v + r);
    }
    sB[ty][tx] = lb;
    __syncthreads();
    if (ty == 0) {                     // per-column backward carry scan
        int u = BIGI;
        #pragma unroll
        for (int s = NSEG - 1; s >= 0; --s) {
            u = min(sB[s][tx], u + L);
            sB[s][tx] = u;             // U[s]: final value at first row of seg s
        }
    }
    __syncthreads();
    int prevb = (ty == NSEG - 1) ? BIGI : sB[ty + 1][tx];
    #pragma unroll
    for (int r = L - 1; r >= 0; --r) { // backward pass + write g^2
        int v = min(gf[r], prevb + 1);
        prevb = v;
        float fv = (float)v;
        out[(size_t)(i0 + r) * W] = fv * fv;
    }
}

// ---------------- exact row EDT (windowed outward scan) + per-block min/max ----------------
__global__ void row_edt(float* __restrict__ g2pos,
                        float* __restrict__ g2neg,
                        float* __restrict__ rowmm) {
    __shared__ float row[W];
    __shared__ float smn[8], smx[8];

    int blk = blockIdx.x;                 // 0 .. 2*B*H-1
    int which = blk / (B * H);
    int rr = blk - which * (B * H);
    int b = rr / H;
    int i = rr - b * H;

    float* buf = (which ? g2neg : g2pos) + ((size_t)b * H + i) * W;
    int j = threadIdx.x;
    float g2 = buf[j];
    row[j] = g2;
    __syncthreads();

    float best = g2;
    for (int r = 1; r < W; ++r) {
        float r2 = (float)(r * r);
        if (r2 >= best) break;            // exact termination
        int jl = j - r, jr = j + r;
        if (jl >= 0) best = fminf(best, row[jl] + r2);
        if (jr < W)  best = fminf(best, row[jr] + r2);
    }
    buf[j] = best;                        // d2 in place

    float mn = best, mx = best;
    for (int off = 32; off >= 1; off >>= 1) {
        mn = fminf(mn, __shfl_down(mn, off));
        mx = fmaxf(mx, __shfl_down(mx, off));
    }
    int wave = threadIdx.x >> 6, lane = threadIdx.x & 63;
    if (lane == 0) { smn[wave] = mn; smx[wave] = mx; }
    __syncthreads();
    if (threadIdx.x == 0) {
        float a = smn[0], bx = smx[0];
        #pragma unroll
        for (int w = 1; w < 8; ++w) { a = fminf(a, smn[w]); bx = fmaxf(bx, smx[w]); }
        rowmm[blk * 2]     = a;
        rowmm[blk * 2 + 1] = bx;
    }
}

// ---------------- per-(which,batch) stats ----------------
__global__ void stats_reduce(const float* __restrict__ rowmm,
                             float* __restrict__ stats) {
    __shared__ float smn[8], smx[8];
    int which = blockIdx.x >> 3;
    int b = blockIdx.x & 7;
    int t = threadIdx.x;
    int base = ((which * B + b) * H + t) * 2;
    float mn = rowmm[base], mx = rowmm[base + 1];
    for (int off = 32; off >= 1; off >>= 1) {
        mn = fminf(mn, __shfl_down(mn, off));
        mx = fmaxf(mx, __shfl_down(mx, off));
    }
    int wave = t >> 6, lane = t & 63;
    if (lane == 0) { smn[wave] = mn; smx[wave] = mx; }
    __syncthreads();
    if (t == 0) {
        float a = smn[0], bx = smx[0];
        #pragma unroll
        for (int w = 1; w < 8; ++w) { a = fminf(a, smn[w]); bx = fmaxf(bx, smx[w]); }
        float dmin = sqrtf(a), dmax = sqrtf(bx);
        float inv = (dmax > dmin) ? 1.0f / (dmax - dmin) : 0.0f;
        stats[b * 4 + which * 2]     = dmin;
        stats[b * 4 + which * 2 + 1] = inv;
    }
}

// ---------------- fused sdf + boundary + sigmoid-sum + reduction ----------------
__global__ void final_reduce(const float* __restrict__ ypred,
                             const float* __restrict__ ytrue,
                             const float* __restrict__ d2pos,
                             const float* __restrict__ d2neg,
                             const float* __restrict__ stats,
                             double* __restrict__ partials) {
    __shared__ float sacc[4];
    int tid = blockIdx.x * blockDim.x + threadIdx.x;
    int stride = gridDim.x * blockDim.x;
    float local = 0.f;
    for (int p = tid; p < NPIX; p += stride) {
        int b = p / (H * W);
        int ij = p - b * (H * W);
        int i = ij / W;
        int j = ij - i * W;

        float posdis = sqrtf(d2pos[p]);
        float negdis = sqrtf(d2neg[p]);
        float pmin = stats[b * 4 + 0];
        float invp = stats[b * 4 + 1];
        float nmin = stats[b * 4 + 2];
        float invn = stats[b * 4 + 3];
        float sdf = (negdis - nmin) * invn - (posdis - pmin) * invp;

        const float* m = ytrue + ((size_t)b * C + SEL) * H * W;
        bool c = m[ij] != 0.f;
        if (c) {
            bool l = (j == 0)     ? true : (m[ij - 1] != 0.f);
            bool r = (j == W - 1) ? true : (m[ij + 1] != 0.f);
            bool u = (i == 0)     ? true : (m[ij - W] != 0.f);
            bool d = (i == H - 1) ? true : (m[ij + W] != 0.f);
            if (!(l && r && u && d)) sdf = 0.f;
        }

        const float* yp = ypred + (size_t)b * C * H * W + ij;
        float s = 0.f;
        #pragma unroll
        for (int cc = 0; cc < C; ++cc) {
            float x = yp[(size_t)cc * H * W];
            s += 1.0f / (1.0f + expf(-x));
        }
        local += s * sdf;
    }
    for (int off = 32; off >= 1; off >>= 1) local += __shfl_down(local, off);
    int wave = threadIdx.x >> 6, lane = threadIdx.x & 63;
    if (lane == 0) sacc[wave] = local;
    __syncthreads();
    if (threadIdx.x == 0) {
        float tot = sacc[0] + sacc[1] + sacc[2] + sacc[3];
        partials[blockIdx.x] = (double)tot;
    }
}

__global__ void finalize(const double* __restrict__ partials, float* __restrict__ out) {
    __shared__ double sd[4];
    double s = 0.0;
    for (int p = threadIdx.x; p < NPART; p += blockDim.x) s += partials[p];
    for (int off = 32; off >= 1; off >>= 1) s += __shfl_down(s, off);
    int wave = threadIdx.x >> 6, lane = threadIdx.x & 63;
    if (lane == 0) sd[wave] = s;
    __syncthreads();
    if (threadIdx.x == 0) {
        double t = sd[0] + sd[1] + sd[2] + sd[3];
        out[0] = (float)(t / (double)((size_t)B * C * H * W));
    }
}

extern "C" void kernel_launch(void* const* d_in, const int* in_sizes, int n_in,
                              void* d_out, int out_size, void* d_ws, size_t ws_size,
                              hipStream_t stream) {
    const float* ypred = (const float*)d_in[0];
    const float* ytrue = (const float*)d_in[1];
    float* out = (float*)d_out;

    float* g2pos = (float*)d_ws;                  // NPIX floats (becomes d2pos)
    float* g2neg = g2pos + NPIX;                  // NPIX floats (becomes d2neg)
    float* stats = g2neg + NPIX;                  // B*4 floats {pmin,invp,nmin,invn}
    float* rowmm = stats + B * 4;                 // 2*B*H*2 floats (mn,mx)
    double* partials = (double*)(rowmm + 2 * B * H * 2);

    col_pass_seg<<<2 * B * (W / TC), TC * NSEG, 0, stream>>>(ytrue, g2pos, g2neg);
    row_edt<<<2 * B * H, W, 0, stream>>>(g2pos, g2neg, rowmm);
    stats_reduce<<<16, W, 0, stream>>>(rowmm, stats);
    final_reduce<<<NPART, 256, 0, stream>>>(ypred, ytrue, g2pos, g2neg, stats, partials);
    finalize<<<1, 256, 0, stream>>>(partials, out);
}

// Round 4
// 49.296 us; speedup vs baseline: 4.8674x; 1.0185x over previous
//
#include <hip/hip_runtime.h>
#include <math.h>

#define B 8
#define C 4
#define H 512
#define W 512
#define SEL 1
#define BIGI 1024       // H + W
#define NPIX (B*H*W)

// ---------------- segmented vertical EDT pass (exact min-plus scan), u16 output ----------------
#define L 32
#define NSEG 16
#define TC 32

__global__ __launch_bounds__(512) void col_pass_seg(const float* __restrict__ ytrue,
                                                    unsigned short* __restrict__ gpos,
                                                    unsigned short* __restrict__ gneg) {
    __shared__ int sA[NSEG][TC];   // lf -> D
    __shared__ int sB[NSEG][TC];   // lb -> U

    int blk = blockIdx.x;              // 2 * B * (W/TC) = 256
    int which = blk >> 7;              // / (B * 16)
    int rem = blk & 127;
    int b = rem >> 4;
    int jt = rem & 15;
    int tx = threadIdx.x & (TC - 1);
    int ty = threadIdx.x / TC;
    int j = jt * TC + tx;
    int i0 = ty * L;

    const float* m = ytrue + ((size_t)b * C + SEL) * H * W + j;
    unsigned short* out = (which ? gneg : gpos) + (size_t)b * H * W + j;

    // local forward scan (registers, statically indexed)
    int gf[L];
    int prev = BIGI;
    #pragma unroll
    for (int r = 0; r < L; ++r) {
        float mv = m[(size_t)(i0 + r) * W];
        bool fg = (mv != 0.0f);
        if (which) fg = !fg;
        int f = fg ? BIGI : 0;
        int v = min(f, prev + 1);
        gf[r] = v;
        prev = v;
    }
    sA[ty][tx] = prev;
    __syncthreads();
    if (ty == 0) {                     // per-column forward carry scan over segments
        int d = BIGI;
        #pragma unroll
        for (int s = 0; s < NSEG; ++s) {
            d = min(sA[s][tx], d + L);
            sA[s][tx] = d;
        }
    }
    __syncthreads();
    int carry = (ty == 0) ? BIGI : sA[ty - 1][tx];
    int lb = 0x7FFFFFFF;
    #pragma unroll
    for (int r = 0; r < L; ++r) {      // fix forward + local backward summary
        int v = min(gf[r], carry + 1 + r);
        gf[r] = v;
        lb = min(lb, v + r);
    }
    sB[ty][tx] = lb;
    __syncthreads();
    if (ty == 0) {                     // per-column backward carry scan
        int u = BIGI;
        #pragma unroll
        for (int s = NSEG - 1; s >= 0; --s) {
            u = min(sB[s][tx], u + L);
            sB[s][tx] = u;
        }
    }
    __syncthreads();
    int prevb = (ty == NSEG - 1) ? BIGI : sB[ty + 1][tx];
    #pragma unroll
    for (int r = L - 1; r >= 0; --r) { // backward pass + write g (u16)
        int v = min(gf[r], prevb + 1);
        prevb = v;
        out[(size_t)(i0 + r) * W] = (unsigned short)v;
    }
}

// ---------------- fused row EDT (pos+neg) + boundary + sigmoid + per-row partials ----------------
// one block (512 threads) per (batch, row). rowpart[blk*8+k]:
// {mn_d2pos, mx_d2pos, mn_d2neg, mx_d2neg, sum s*posdis, sum s*negdis, sum s, pad}
__global__ __launch_bounds__(512) void row_fused(const unsigned short* __restrict__ gpos,
                                                 const unsigned short* __restrict__ gneg,
                                                 const float* __restrict__ ypred,
                                                 float* __restrict__ rowpart) {
    __shared__ float rp[W], rn[W];
    __shared__ float sw[7][8];

    int blk = blockIdx.x;                 // 0 .. B*H-1
    int b = blk >> 9;
    int i = blk & (H - 1);
    int j = threadIdx.x;

    size_t base = ((size_t)b * H + i) * W + j;
    int gp = gpos[base];
    int gn = gneg[base];
    float g2p = (float)(gp * gp);
    float g2n = (float)(gn * gn);
    rp[j] = g2p;
    rn[j] = g2n;
    __syncthreads();

    // exact outward scans (integer-valued f32, early termination exact)
    float bp = g2p;
    for (int r = 1; r < W; ++r) {
        float r2 = (float)(r * r);
        if (r2 >= bp) break;
        int jl = j - r, jr = j + r;
        if (jl >= 0) bp = fminf(bp, rp[jl] + r2);
        if (jr < W)  bp = fminf(bp, rp[jr] + r2);
    }
    float bn = g2n;
    for (int r = 1; r < W; ++r) {
        float r2 = (float)(r * r);
        if (r2 >= bn) break;
        int jl = j - r, jr = j + r;
        if (jl >= 0) bn = fminf(bn, rn[jl] + r2);
        if (jr < W)  bn = fminf(bn, rn[jr] + r2);
    }

    float posdis = sqrtf(bp);
    float negdis = sqrtf(bn);

    // inner boundary <=> d2pos == 1 (fg pixel with in-image bg 4-neighbor)
    bool bnd = (bp == 1.0f);

    // sigmoid sum over channels
    const float* yp = ypred + ((size_t)b * C * H + i) * W + j;
    float s = 0.f;
    #pragma unroll
    for (int cc = 0; cc < C; ++cc) {
        float x = yp[(size_t)cc * H * W];
        s += 1.0f / (1.0f + expf(-x));
    }
    float se = bnd ? 0.f : s;

    float mnp = bp, mxp = bp, mnn = bn, mxn = bn;
    float A = se * posdis, Bv = se * negdis, S = se;
    for (int off = 32; off >= 1; off >>= 1) {
        mnp = fminf(mnp, __shfl_down(mnp, off));
        mxp = fmaxf(mxp, __shfl_down(mxp, off));
        mnn = fminf(mnn, __shfl_down(mnn, off));
        mxn = fmaxf(mxn, __shfl_down(mxn, off));
        A  += __shfl_down(A, off);
        Bv += __shfl_down(Bv, off);
        S  += __shfl_down(S, off);
    }
    int wave = threadIdx.x >> 6, lane = threadIdx.x & 63;
    if (lane == 0) {
        sw[0][wave] = mnp; sw[1][wave] = mxp; sw[2][wave] = mnn; sw[3][wave] = mxn;
        sw[4][wave] = A;   sw[5][wave] = Bv;  sw[6][wave] = S;
    }
    __syncthreads();
    if (threadIdx.x == 0) {
        float a0 = sw[0][0], a1 = sw[1][0], a2 = sw[2][0], a3 = sw[3][0];
        float a4 = sw[4][0], a5 = sw[5][0], a6 = sw[6][0];
        #pragma unroll
        for (int w = 1; w < 8; ++w) {
            a0 = fminf(a0, sw[0][w]); a1 = fmaxf(a1, sw[1][w]);
            a2 = fminf(a2, sw[2][w]); a3 = fmaxf(a3, sw[3][w]);
            a4 += sw[4][w]; a5 += sw[5][w]; a6 += sw[6][w];
        }
        float* rpo = rowpart + (size_t)blk * 8;
        rpo[0] = a0; rpo[1] = a1; rpo[2] = a2; rpo[3] = a3;
        rpo[4] = a4; rpo[5] = a5; rpo[6] = a6; rpo[7] = 0.f;
    }
}

// ---------------- per-batch stats + final total (single block, deterministic) ----------------
__global__ __launch_bounds__(512) void batch_final(const float* __restrict__ rowpart,
                                                   float* __restrict__ out) {
    __shared__ float sw[7][8];
    int t = threadIdx.x;
    int wave = t >> 6, lane = t & 63;
    double dtot = 0.0;

    for (int b = 0; b < B; ++b) {
        const float4* rpv = (const float4*)(rowpart + ((size_t)(b * H + t)) * 8);
        float4 lo = rpv[0];
        float4 hi = rpv[1];
        float mnp = lo.x, mxp = lo.y, mnn = lo.z, mxn = lo.w;
        float A = hi.x, Bv = hi.y, S = hi.z;
        for (int off = 32; off >= 1; off >>= 1) {
            mnp = fminf(mnp, __shfl_down(mnp, off));
            mxp = fmaxf(mxp, __shfl_down(mxp, off));
            mnn = fminf(mnn, __shfl_down(mnn, off));
            mxn = fmaxf(mxn, __shfl_down(mxn, off));
            A  += __shfl_down(A, off);
            Bv += __shfl_down(Bv, off);
            S  += __shfl_down(S, off);
        }
        if (lane == 0) {
            sw[0][wave] = mnp; sw[1][wave] = mxp; sw[2][wave] = mnn; sw[3][wave] = mxn;
            sw[4][wave] = A;   sw[5][wave] = Bv;  sw[6][wave] = S;
        }
        __syncthreads();
        if (t == 0) {
            float a0 = sw[0][0], a1 = sw[1][0], a2 = sw[2][0], a3 = sw[3][0];
            float a4 = sw[4][0], a5 = sw[5][0], a6 = sw[6][0];
            #pragma unroll
            for (int w = 1; w < 8; ++w) {
                a0 = fminf(a0, sw[0][w]); a1 = fmaxf(a1, sw[1][w]);
                a2 = fminf(a2, sw[2][w]); a3 = fmaxf(a3, sw[3][w]);
                a4 += sw[4][w]; a5 += sw[5][w]; a6 += sw[6][w];
            }
            float pmin = sqrtf(a0), pmax = sqrtf(a1);
            float nmin = sqrtf(a2), nmax = sqrtf(a3);
            float invp = (pmax > pmin) ? 1.0f / (pmax - pmin) : 0.0f;
            float invn = (nmax > nmin) ? 1.0f / (nmax - nmin) : 0.0f;
            dtot += (double)(invn * a5 - invp * a4 - (nmin * invn - pmin * invp) * a6);
        }
        __syncthreads();
    }
    if (t == 0) out[0] = (float)(dtot / (double)((size_t)B * C * H * W));
}

extern "C" void kernel_launch(void* const* d_in, const int* in_sizes, int n_in,
                              void* d_out, int out_size, void* d_ws, size_t ws_size,
                              hipStream_t stream) {
    const float* ypred = (const float*)d_in[0];
    const float* ytrue = (const float*)d_in[1];
    float* out = (float*)d_out;

    unsigned short* gpos = (unsigned short*)d_ws;    // NPIX u16
    unsigned short* gneg = gpos + NPIX;              // NPIX u16
    float* rowpart = (float*)(gneg + NPIX);          // B*H*8 floats (16B aligned: 8MB offset)

    col_pass_seg<<<2 * B * (W / TC), TC * NSEG, 0, stream>>>(ytrue, gpos, gneg);
    row_fused<<<B * H, W, 0, stream>>>(gpos, gneg, ypred, rowpart);
    batch_final<<<1, W, 0, stream>>>(rowpart, out);
}

// Round 5
// 40.863 us; speedup vs baseline: 5.8718x; 1.2064x over previous
//
#include <hip/hip_runtime.h>
#include <math.h>

#define B 8
#define C 4
#define H 512
#define W 512
#define SEL 1
#define BIGI 1024       // H + W
#define NPIX (B*H*W)
#define CH 128          // rows per chunk
#define RC 4            // chunks per column
#define TC 32           // columns per block
#define NSEG 16         // segments per chunk
#define LL 8            // rows per thread (CH/NSEG)
#define CINF 3000       // "infinite" carry (any candidate > 1024 never wins)

// ---------------- local (per-chunk) vertical EDT, both polarities, packed u32 out ----------------
__global__ __launch_bounds__(512) void col_two_level(const float* __restrict__ ytrue,
                                                     unsigned* __restrict__ gpk,
                                                     unsigned short* __restrict__ sums) {
    __shared__ int sAp[NSEG][TC], sAn[NSEG][TC], sBp[NSEG][TC], sBn[NSEG][TC];
    int blk = blockIdx.x;              // B * 16 tiles * RC = 512
    int b   = blk >> 6;
    int rem = blk & 63;
    int jt  = rem >> 2;
    int rc  = rem & 3;
    int tx  = threadIdx.x & (TC - 1);
    int ty  = threadIdx.x / TC;
    int j   = jt * TC + tx;
    int i0  = rc * CH + ty * LL;

    const float* m = ytrue + ((size_t)b * C + SEL) * H * W + j;
    int gfp[LL], gfn[LL];
    int pp = BIGI, pn = BIGI;
    #pragma unroll
    for (int r = 0; r < LL; ++r) {     // local forward scan, both polarities
        float mv = m[(size_t)(i0 + r) * W];
        bool fg = (mv != 0.0f);
        int vp = fg ? BIGI : 0;
        int vn = fg ? 0 : BIGI;
        vp = min(vp, pp + 1); gfp[r] = vp; pp = vp;
        vn = min(vn, pn + 1); gfn[r] = vn; pn = vn;
    }
    sAp[ty][tx] = pp; sAn[ty][tx] = pn;
    __syncthreads();
    if (ty == 0) {                     // forward carry over segments (per column)
        int dp = BIGI, dn = BIGI;
        #pragma unroll
        for (int s = 0; s < NSEG; ++s) {
            dp = min(sAp[s][tx], dp + LL); sAp[s][tx] = dp;
            dn = min(sAn[s][tx], dn + LL); sAn[s][tx] = dn;
        }
    }
    __syncthreads();
    int cp = ty ? sAp[ty - 1][tx] : BIGI;
    int cn = ty ? sAn[ty - 1][tx] : BIGI;
    int lbp = 1 << 20, lbn = 1 << 20;
    #pragma unroll
    for (int r = 0; r < LL; ++r) {     // forward fix + local backward summary
        int vp = min(gfp[r], cp + 1 + r); gfp[r] = vp; lbp = min(lbp, vp + r);
        int vn = min(gfn[r], cn + 1 + r); gfn[r] = vn; lbn = min(lbn, vn + r);
    }
    sBp[ty][tx] = lbp; sBn[ty][tx] = lbn;
    __syncthreads();
    if (ty == 0) {                     // backward carry over segments + chunk summaries
        int up = BIGI, un = BIGI;
        #pragma unroll
        for (int s = NSEG - 1; s >= 0; --s) {
            up = min(sBp[s][tx], up + LL); sBp[s][tx] = up;
            un = min(sBn[s][tx], un + LL); sBn[s][tx] = un;
        }
        unsigned short* sp = sums + (((size_t)(b * RC + rc)) * W + j) * 4;
        sp[0] = (unsigned short)sAp[NSEG - 1][tx];   // D_p (resolved fwd at chunk end)
        sp[1] = (unsigned short)up;                  // U_p (resolved bwd at chunk start)
        sp[2] = (unsigned short)sAn[NSEG - 1][tx];   // D_n
        sp[3] = (unsigned short)un;                  // U_n
    }
    __syncthreads();
    int pbp = (ty == NSEG - 1) ? BIGI : sBp[ty + 1][tx];
    int pbn = (ty == NSEG - 1) ? BIGI : sBn[ty + 1][tx];
    unsigned* op = gpk + ((size_t)b * H + i0) * W + j;
    #pragma unroll
    for (int r = LL - 1; r >= 0; --r) { // local backward pass + packed store
        int vp = min(gfp[r], pbp + 1); pbp = vp;
        int vn = min(gfn[r], pbn + 1); pbn = vn;
        op[(size_t)r * W] = (unsigned)vp | ((unsigned)vn << 16);
    }
}

// ---------------- inter-chunk carries: A_c = min_{c'<c}(D-e), B_c = min_{c'>c}(U+s) ----------------
__global__ void carry_scan(const unsigned short* __restrict__ sums,
                           short* __restrict__ car) {
    int t = blockIdx.x * 256 + threadIdx.x;   // B*W = 4096
    if (t >= B * W) return;
    int b = t >> 9;
    int j = t & (W - 1);
    ushort4 sv[RC];
    #pragma unroll
    for (int rc = 0; rc < RC; ++rc)
        sv[rc] = *(const ushort4*)(sums + (((size_t)(b * RC + rc)) * W + j) * 4);
    int Ap = CINF, An = CINF;
    short oA[RC][2];
    #pragma unroll
    for (int rc = 0; rc < RC; ++rc) {
        oA[rc][0] = (short)Ap;
        oA[rc][1] = (short)An;
        int e = rc * CH + CH - 1;
        Ap = min(Ap, (int)sv[rc].x - e);
        An = min(An, (int)sv[rc].z - e);
    }
    int Bp = CINF, Bn = CINF;
    #pragma unroll
    for (int rc = RC - 1; rc >= 0; --rc) {
        short4 o;
        o.x = oA[rc][0];
        o.y = (short)Bp;
        o.z = oA[rc][1];
        o.w = (short)Bn;
        *(short4*)(car + (((size_t)(b * RC + rc)) * W + j) * 4) = o;
        int s0 = rc * CH;
        Bp = min(Bp, (int)sv[rc].y + s0);
        Bn = min(Bn, (int)sv[rc].w + s0);
    }
}

// ---------------- fused row EDT + boundary + sigmoid + per-row partials ----------------
__global__ __launch_bounds__(512) void row_fused(const unsigned* __restrict__ gpk,
                                                 const short* __restrict__ car,
                                                 const float* __restrict__ ypred,
                                                 float* __restrict__ rowpart) {
    __shared__ float rp[W], rn[W];
    __shared__ float sw[7][8];

    int blk = blockIdx.x;                 // 0 .. B*H-1
    int b = blk >> 9;
    int i = blk & (H - 1);
    int rc = i >> 7;
    int j = threadIdx.x;

    unsigned gv = gpk[((size_t)b * H + i) * W + j];
    short4 cv = *(const short4*)(car + (((size_t)(b * RC + rc)) * W + j) * 4);
    int gp = (int)(gv & 0xFFFFu), gn = (int)(gv >> 16);
    gp = min(gp, min((int)cv.x + i, (int)cv.y - i));   // cross-chunk fix (exact)
    gn = min(gn, min((int)cv.z + i, (int)cv.w - i));
    float g2p = (float)(gp * gp);
    float g2n = (float)(gn * gn);
    rp[j] = g2p;
    rn[j] = g2n;
    __syncthreads();

    float bp = g2p;
    for (int r = 1; r < W; ++r) {
        float r2 = (float)(r * r);
        if (r2 >= bp) break;              // exact termination
        int jl = j - r, jr = j + r;
        if (jl >= 0) bp = fminf(bp, rp[jl] + r2);
        if (jr < W)  bp = fminf(bp, rp[jr] + r2);
    }
    float bn = g2n;
    for (int r = 1; r < W; ++r) {
        float r2 = (float)(r * r);
        if (r2 >= bn) break;
        int jl = j - r, jr = j + r;
        if (jl >= 0) bn = fminf(bn, rn[jl] + r2);
        if (jr < W)  bn = fminf(bn, rn[jr] + r2);
    }

    float posdis = sqrtf(bp);
    float negdis = sqrtf(bn);
    bool bnd = (bp == 1.0f);              // inner 4-boundary <=> d2pos == 1

    const float* yp = ypred + ((size_t)b * C * H + i) * W + j;
    float s = 0.f;
    #pragma unroll
    for (int cc = 0; cc < C; ++cc) {
        float x = yp[(size_t)cc * H * W];
        s += 1.0f / (1.0f + expf(-x));
    }
    float se = bnd ? 0.f : s;

    float mnp = bp, mxp = bp, mnn = bn, mxn = bn;
    float A = se * posdis, Bv = se * negdis, S = se;
    for (int off = 32; off >= 1; off >>= 1) {
        mnp = fminf(mnp, __shfl_down(mnp, off));
        mxp = fmaxf(mxp, __shfl_down(mxp, off));
        mnn = fminf(mnn, __shfl_down(mnn, off));
        mxn = fmaxf(mxn, __shfl_down(mxn, off));
        A  += __shfl_down(A, off);
        Bv += __shfl_down(Bv, off);
        S  += __shfl_down(S, off);
    }
    int wave = threadIdx.x >> 6, lane = threadIdx.x & 63;
    if (lane == 0) {
        sw[0][wave] = mnp; sw[1][wave] = mxp; sw[2][wave] = mnn; sw[3][wave] = mxn;
        sw[4][wave] = A;   sw[5][wave] = Bv;  sw[6][wave] = S;
    }
    __syncthreads();
    if (threadIdx.x == 0) {
        float a0 = sw[0][0], a1 = sw[1][0], a2 = sw[2][0], a3 = sw[3][0];
        float a4 = sw[4][0], a5 = sw[5][0], a6 = sw[6][0];
        #pragma unroll
        for (int w = 1; w < 8; ++w) {
            a0 = fminf(a0, sw[0][w]); a1 = fmaxf(a1, sw[1][w]);
            a2 = fminf(a2, sw[2][w]); a3 = fmaxf(a3, sw[3][w]);
            a4 += sw[4][w]; a5 += sw[5][w]; a6 += sw[6][w];
        }
        float* rpo = rowpart + (size_t)blk * 8;
        rpo[0] = a0; rpo[1] = a1; rpo[2] = a2; rpo[3] = a3;
        rpo[4] = a4; rpo[5] = a5; rpo[6] = a6; rpo[7] = 0.f;
    }
}

// ---------------- per-batch stats + total: one wave per batch ----------------
__global__ __launch_bounds__(512) void batch_final(const float* __restrict__ rowpart,
                                                   float* __restrict__ out) {
    __shared__ double sacc[8];
    int bw = threadIdx.x >> 6;            // wave = batch
    int lane = threadIdx.x & 63;
    float mnp = 3.4e38f, mxp = 0.f, mnn = 3.4e38f, mxn = 0.f;
    float A = 0.f, Bv = 0.f, S = 0.f;
    #pragma unroll
    for (int k = 0; k < 8; ++k) {
        int r = lane + 64 * k;
        const float4* rv = (const float4*)(rowpart + ((size_t)(bw * H + r)) * 8);
        float4 lo = rv[0], hi = rv[1];
        mnp = fminf(mnp, lo.x); mxp = fmaxf(mxp, lo.y);
        mnn = fminf(mnn, lo.z); mxn = fmaxf(mxn, lo.w);
        A += hi.x; Bv += hi.y; S += hi.z;
    }
    for (int off = 32; off >= 1; off >>= 1) {
        mnp = fminf(mnp, __shfl_down(mnp, off));
        mxp = fmaxf(mxp, __shfl_down(mxp, off));
        mnn = fminf(mnn, __shfl_down(mnn, off));
        mxn = fmaxf(mxn, __shfl_down(mxn, off));
        A  += __shfl_down(A, off);
        Bv += __shfl_down(Bv, off);
        S  += __shfl_down(S, off);
    }
    if (lane == 0) {
        float pmin = sqrtf(mnp), pmax = sqrtf(mxp);
        float nmin = sqrtf(mnn), nmax = sqrtf(mxn);
        float invp = (pmax > pmin) ? 1.0f / (pmax - pmin) : 0.0f;
        float invn = (nmax > nmin) ? 1.0f / (nmax - nmin) : 0.0f;
        sacc[bw] = (double)(invn * Bv - invp * A - (nmin * invn - pmin * invp) * S);
    }
    __syncthreads();
    if (threadIdx.x == 0) {
        double tt = 0.0;
        #pragma unroll
        for (int q = 0; q < 8; ++q) tt += sacc[q];
        out[0] = (float)(tt / (double)((size_t)B * C * H * W));
    }
}

extern "C" void kernel_launch(void* const* d_in, const int* in_sizes, int n_in,
                              void* d_out, int out_size, void* d_ws, size_t ws_size,
                              hipStream_t stream) {
    const float* ypred = (const float*)d_in[0];
    const float* ytrue = (const float*)d_in[1];
    float* out = (float*)d_out;

    unsigned* gpk = (unsigned*)d_ws;                        // NPIX u32 (gp | gn<<16) = 8 MB
    unsigned short* sums = (unsigned short*)(gpk + NPIX);   // B*RC*W*4 u16 = 128 KB
    short* car = (short*)(sums + (size_t)B * RC * W * 4);   // B*RC*W*4 i16 = 128 KB
    float* rowpart = (float*)(car + (size_t)B * RC * W * 4);// B*H*8 f32 = 128 KB (16B-aligned)

    col_two_level<<<512, 512, 0, stream>>>(ytrue, gpk, sums);
    carry_scan<<<16, 256, 0, stream>>>(sums, car);
    row_fused<<<B * H, W, 0, stream>>>(gpk, car, ypred, rowpart);
    batch_final<<<1, 512, 0, stream>>>(rowpart, out);
}

// Round 6
// 24.852 us; speedup vs baseline: 9.6548x; 1.6442x over previous
//
#include <hip/hip_runtime.h>
#include <math.h>

#define B 8
#define C 4
#define H 512
#define W 512
#define SEL 1
#define BIGI 1024       // H + W
#define NPIX (B*H*W)
#define CH 128          // rows per chunk
#define RC 4            // chunks per column
#define TC 32           // columns per block
#define NSEG 16         // segments per chunk
#define LL 8            // rows per thread (CH/NSEG)
#define CINF 3000       // "infinite" carry (any candidate > 1024 never wins)
#define G 4             // rows per row_fused block

// ---------------- local (per-chunk) vertical EDT, both polarities, packed u32 out ----------------
__global__ __launch_bounds__(512) void col_two_level(const float* __restrict__ ytrue,
                                                     unsigned* __restrict__ gpk,
                                                     unsigned short* __restrict__ sums) {
    __shared__ int sAp[NSEG][TC], sAn[NSEG][TC], sBp[NSEG][TC], sBn[NSEG][TC];
    int blk = blockIdx.x;              // B * 16 tiles * RC = 512
    int b   = blk >> 6;
    int rem = blk & 63;
    int jt  = rem >> 2;
    int rc  = rem & 3;
    int tx  = threadIdx.x & (TC - 1);
    int ty  = threadIdx.x / TC;
    int j   = jt * TC + tx;
    int i0  = rc * CH + ty * LL;

    const float* m = ytrue + ((size_t)b * C + SEL) * H * W + j;
    int gfp[LL], gfn[LL];
    int pp = BIGI, pn = BIGI;
    #pragma unroll
    for (int r = 0; r < LL; ++r) {     // local forward scan, both polarities
        float mv = m[(size_t)(i0 + r) * W];
        bool fg = (mv != 0.0f);
        int vp = fg ? BIGI : 0;
        int vn = fg ? 0 : BIGI;
        vp = min(vp, pp + 1); gfp[r] = vp; pp = vp;
        vn = min(vn, pn + 1); gfn[r] = vn; pn = vn;
    }
    sAp[ty][tx] = pp; sAn[ty][tx] = pn;
    __syncthreads();
    if (ty == 0) {                     // forward carry over segments (per column)
        int dp = BIGI, dn = BIGI;
        #pragma unroll
        for (int s = 0; s < NSEG; ++s) {
            dp = min(sAp[s][tx], dp + LL); sAp[s][tx] = dp;
            dn = min(sAn[s][tx], dn + LL); sAn[s][tx] = dn;
        }
    }
    __syncthreads();
    int cp = ty ? sAp[ty - 1][tx] : BIGI;
    int cn = ty ? sAn[ty - 1][tx] : BIGI;
    int lbp = 1 << 20, lbn = 1 << 20;
    #pragma unroll
    for (int r = 0; r < LL; ++r) {     // forward fix + local backward summary
        int vp = min(gfp[r], cp + 1 + r); gfp[r] = vp; lbp = min(lbp, vp + r);
        int vn = min(gfn[r], cn + 1 + r); gfn[r] = vn; lbn = min(lbn, vn + r);
    }
    sBp[ty][tx] = lbp; sBn[ty][tx] = lbn;
    __syncthreads();
    if (ty == 0) {                     // backward carry over segments + chunk summaries
        int up = BIGI, un = BIGI;
        #pragma unroll
        for (int s = NSEG - 1; s >= 0; --s) {
            up = min(sBp[s][tx], up + LL); sBp[s][tx] = up;
            un = min(sBn[s][tx], un + LL); sBn[s][tx] = un;
        }
        unsigned short* sp = sums + (((size_t)(b * RC + rc)) * W + j) * 4;
        sp[0] = (unsigned short)sAp[NSEG - 1][tx];   // D_p (resolved fwd at chunk end)
        sp[1] = (unsigned short)up;                  // U_p (resolved bwd at chunk start)
        sp[2] = (unsigned short)sAn[NSEG - 1][tx];   // D_n
        sp[3] = (unsigned short)un;                  // U_n
    }
    __syncthreads();
    int pbp = (ty == NSEG - 1) ? BIGI : sBp[ty + 1][tx];
    int pbn = (ty == NSEG - 1) ? BIGI : sBn[ty + 1][tx];
    unsigned* op = gpk + ((size_t)b * H + i0) * W + j;
    #pragma unroll
    for (int r = LL - 1; r >= 0; --r) { // local backward pass + packed store
        int vp = min(gfp[r], pbp + 1); pbp = vp;
        int vn = min(gfn[r], pbn + 1); pbn = vn;
        op[(size_t)r * W] = (unsigned)vp | ((unsigned)vn << 16);
    }
}

// ---------------- fused row EDT (4 rows/block) + boundary + sigmoid + partials ----------------
// rowpart[blk] = {mx_d2pos, mx_d2neg, sum s*posdis, sum s*negdis} (mins are exactly 0:
// background pixels have d2pos=0, foreground have d2neg=0; degenerate batches guarded in final)
__global__ __launch_bounds__(512) void row_fused(const unsigned* __restrict__ gpk,
                                                 const unsigned short* __restrict__ sums,
                                                 const float* __restrict__ ypred,
                                                 float* __restrict__ rowpart) {
    __shared__ float2 s2[G][W];
    __shared__ float sw[4][8];

    int blk = blockIdx.x;                 // B*H/G = 1024
    int b = blk >> 7;
    int g = blk & 127;
    int i0 = g * G;
    int rc = i0 >> 7;                     // all G rows in same chunk (G | CH)
    int j = threadIdx.x;

    // inline inter-chunk carries from summaries (uniform branches; L2-resident)
    int Ap = CINF, An = CINF, Bp = CINF, Bn = CINF;
    #pragma unroll
    for (int q = 0; q < RC; ++q) {
        if (q != rc) {
            ushort4 sv = *(const ushort4*)(sums + (((size_t)(b * RC + q)) * W + j) * 4);
            if (q < rc) {
                int e = q * CH + CH - 1;
                Ap = min(Ap, (int)sv.x - e);
                An = min(An, (int)sv.z - e);
            } else {
                int s0 = q * CH;
                Bp = min(Bp, (int)sv.y + s0);
                Bn = min(Bn, (int)sv.w + s0);
            }
        }
    }

    #pragma unroll
    for (int r = 0; r < G; ++r) {
        int ii = i0 + r;
        unsigned gv = gpk[((size_t)b * H + ii) * W + j];
        int gp = (int)(gv & 0xFFFFu), gn = (int)(gv >> 16);
        gp = min(gp, min(Ap + ii, Bp - ii));   // cross-chunk fix (exact)
        gn = min(gn, min(An + ii, Bn - ii));
        s2[r][j] = make_float2((float)(gp * gp), (float)(gn * gn));
    }
    __syncthreads();

    float mxp = 0.f, mxn = 0.f, A = 0.f, Bv = 0.f;
    #pragma unroll
    for (int r = 0; r < G; ++r) {
        float2 v0 = s2[r][j];
        float bp = v0.x, bn = v0.y;
        for (int rr = 1; rr < W; ++rr) {      // exact outward scan, both polarities
            float r2 = (float)(rr * rr);
            if (r2 >= bp && r2 >= bn) break;  // unvisited candidates >= r2 -> exact
            int jl = j - rr, jr = j + rr;
            if (jl >= 0) { float2 u = s2[r][jl]; bp = fminf(bp, u.x + r2); bn = fminf(bn, u.y + r2); }
            if (jr < W)  { float2 u = s2[r][jr]; bp = fminf(bp, u.x + r2); bn = fminf(bn, u.y + r2); }
        }
        float posdis = sqrtf(bp);
        float negdis = sqrtf(bn);
        bool bnd = (bp == 1.0f);              // inner 4-boundary <=> d2pos == 1

        const float* yp = ypred + ((size_t)b * C * H + i0 + r) * W + j;
        float s = 0.f;
        #pragma unroll
        for (int cc = 0; cc < C; ++cc) {
            float x = yp[(size_t)cc * H * W];
            s += 1.0f / (1.0f + __expf(-x));
        }
        float se = bnd ? 0.f : s;
        mxp = fmaxf(mxp, bp); mxn = fmaxf(mxn, bn);
        A += se * posdis; Bv += se * negdis;
    }

    for (int off = 32; off >= 1; off >>= 1) {
        mxp = fmaxf(mxp, __shfl_down(mxp, off));
        mxn = fmaxf(mxn, __shfl_down(mxn, off));
        A  += __shfl_down(A, off);
        Bv += __shfl_down(Bv, off);
    }
    int wave = threadIdx.x >> 6, lane = threadIdx.x & 63;
    if (lane == 0) { sw[0][wave] = mxp; sw[1][wave] = mxn; sw[2][wave] = A; sw[3][wave] = Bv; }
    __syncthreads();
    if (threadIdx.x == 0) {
        float a0 = sw[0][0], a1 = sw[1][0], a2 = sw[2][0], a3 = sw[3][0];
        #pragma unroll
        for (int w = 1; w < 8; ++w) {
            a0 = fmaxf(a0, sw[0][w]); a1 = fmaxf(a1, sw[1][w]);
            a2 += sw[2][w]; a3 += sw[3][w];
        }
        *(float4*)(rowpart + (size_t)blk * 4) = make_float4(a0, a1, a2, a3);
    }
}

// ---------------- per-batch stats + total: one wave per batch ----------------
__global__ __launch_bounds__(512) void batch_final(const float* __restrict__ rowpart,
                                                   float* __restrict__ out) {
    __shared__ double sacc[8];
    int bw = threadIdx.x >> 6;            // wave = batch
    int lane = threadIdx.x & 63;
    const float4* rv = (const float4*)(rowpart + (size_t)bw * 128 * 4);
    float4 e0 = rv[lane];
    float4 e1 = rv[lane + 64];
    float mxp = fmaxf(e0.x, e1.x), mxn = fmaxf(e0.y, e1.y);
    float A = e0.z + e1.z, Bv = e0.w + e1.w;
    for (int off = 32; off >= 1; off >>= 1) {
        mxp = fmaxf(mxp, __shfl_down(mxp, off));
        mxn = fmaxf(mxn, __shfl_down(mxn, off));
        A  += __shfl_down(A, off);
        Bv += __shfl_down(Bv, off);
    }
    if (lane == 0) {
        float pmax = sqrtf(mxp), nmax = sqrtf(mxn);
        float invp = (pmax > 0.f) ? 1.0f / pmax : 0.0f;
        float invn = (nmax > 0.f) ? 1.0f / nmax : 0.0f;
        sacc[bw] = (pmax > 0.f) ? (double)(invn * Bv - invp * A) : 0.0;
    }
    __syncthreads();
    if (threadIdx.x == 0) {
        double tt = 0.0;
        #pragma unroll
        for (int q = 0; q < 8; ++q) tt += sacc[q];
        out[0] = (float)(tt / (double)((size_t)B * C * H * W));
    }
}

extern "C" void kernel_launch(void* const* d_in, const int* in_sizes, int n_in,
                              void* d_out, int out_size, void* d_ws, size_t ws_size,
                              hipStream_t stream) {
    const float* ypred = (const float*)d_in[0];
    const float* ytrue = (const float*)d_in[1];
    float* out = (float*)d_out;

    unsigned* gpk = (unsigned*)d_ws;                        // NPIX u32 (gp | gn<<16) = 8 MB
    unsigned short* sums = (unsigned short*)(gpk + NPIX);   // B*RC*W*4 u16 = 128 KB
    float* rowpart = (float*)(sums + (size_t)B * RC * W * 4); // B*(H/G)*4 f32 = 16 KB (16B-aligned)

    col_two_level<<<512, 512, 0, stream>>>(ytrue, gpk, sums);
    row_fused<<<B * H / G, W, 0, stream>>>(gpk, sums, ypred, rowpart);
    batch_final<<<1, 512, 0, stream>>>(rowpart, out);
}